// Round 1
// baseline (123.196 us; speedup 1.0000x reference)
//
#include <hip/hip_runtime.h>

#define LPOS 256
#define CCH 20
#define BB 4096
#define LC 5120  // LPOS*CCH

// ---------------- Kernel 1: seq extraction + linear term -------------------
// One block per batch b (256 threads, thread = position l).
// Writes seqT[l*B + b] (u8) and out[b] = theta0 + sum_l theta_lc[l, s_l].
__global__ __launch_bounds__(256) void k_prepare(
    const float* __restrict__ x_lc, const float* __restrict__ theta_0,
    const float* __restrict__ theta_lc, unsigned char* __restrict__ seqT,
    float* __restrict__ out)
{
    const int b = blockIdx.x;
    const int l = threadIdx.x;
    const float* xp = x_lc + (size_t)b * LC + (size_t)l * CCH;
    // 80 B per thread, 16B-aligned (80 = 5*16): 5 x float4
    const float4* xp4 = reinterpret_cast<const float4*>(xp);
    float v[CCH];
#pragma unroll
    for (int q = 0; q < 5; ++q) {
        float4 t = xp4[q];
        v[q * 4 + 0] = t.x; v[q * 4 + 1] = t.y;
        v[q * 4 + 2] = t.z; v[q * 4 + 3] = t.w;
    }
    int s = 0; float best = v[0];
#pragma unroll
    for (int c = 1; c < CCH; ++c) { if (v[c] > best) { best = v[c]; s = c; } }

    seqT[(size_t)l * BB + b] = (unsigned char)s;

    float lin = theta_lc[l * CCH + s];
    // wave64 shuffle reduce
#pragma unroll
    for (int off = 32; off > 0; off >>= 1) lin += __shfl_down(lin, off, 64);
    __shared__ float partial[4];
    const int wave = threadIdx.x >> 6;
    const int lane = threadIdx.x & 63;
    if (lane == 0) partial[wave] = lin;
    __syncthreads();
    if (threadIdx.x == 0)
        out[b] = theta_0[0] + partial[0] + partial[1] + partial[2] + partial[3];
}

// ---------------- Kernel 2: masked pairwise quadratic form -----------------
// Since x is one-hot and we iterate strictly l2 > l1, the mask is implicit.
// Block (tile, g): batches [tile*1024, tile*1024+1024), rows l1 in {g, 254-g}
// (exactly 256 (l1,l2) pairs per block -> balanced).
// For each chunk of 8 l2 values, stage the 8 x 20 x 20 subtables into LDS,
// then every thread gathers for its 2 batches.
#define QTHREADS 512
#define BPT 2            // batches per thread
#define TILEB 1024       // batches per block
#define NTILES (BB / TILEB)      // 4
#define NGROUPS 128
#define L2CHUNK 8
#define CC2 (CCH * CCH)              // 400
#define CHUNK_ELEMS (L2CHUNK * CC2)  // 3200
#define LOADS_PT ((CHUNK_ELEMS + QTHREADS - 1) / QTHREADS)  // 7

__global__ __launch_bounds__(QTHREADS) void k_quad(
    const float* __restrict__ Theta,          // (5120, 5120), row-major
    const unsigned char* __restrict__ seqT,   // (L, B)
    float* __restrict__ out)
{
    __shared__ float Tl[CHUNK_ELEMS];
    const int tile = blockIdx.x;   // 0..NTILES-1
    const int g    = blockIdx.y;   // 0..127
    const int tid  = threadIdx.x;

    float acc[BPT];
    int bs[BPT];
#pragma unroll
    for (int k = 0; k < BPT; ++k) {
        acc[k] = 0.f;
        bs[k] = tile * TILEB + k * QTHREADS + tid;
    }

    int l1list[2] = { g, 254 - g };
    const int nl1 = (g == 127) ? 1 : 2;

    for (int i = 0; i < nl1; ++i) {
        const int l1 = l1list[i];
        int s1[BPT];
#pragma unroll
        for (int k = 0; k < BPT; ++k)
            s1[k] = seqT[(size_t)l1 * BB + bs[k]];
        const float* Trow = Theta + (size_t)(l1 * CCH) * LC;

        for (int l2s = l1 + 1; l2s < LPOS; l2s += L2CHUNK) {
            const int nj = min(L2CHUNK, LPOS - l2s);
            const int nelem = nj * CC2;
            __syncthreads();  // prior chunk's gathers done before overwrite
#pragma unroll
            for (int q = 0; q < LOADS_PT; ++q) {
                int e = tid + q * QTHREADS;
                if (e < nelem) {
                    int j = e / CC2;
                    int rem = e - j * CC2;
                    int r = rem / CCH;
                    int c = rem - r * CCH;
                    Tl[e] = Trow[(size_t)r * LC + (size_t)(l2s + j) * CCH + c];
                }
            }
            __syncthreads();
            if (nj == L2CHUNK) {
#pragma unroll
                for (int j = 0; j < L2CHUNK; ++j) {
                    const int l2 = l2s + j;
#pragma unroll
                    for (int k = 0; k < BPT; ++k) {
                        int s2 = seqT[(size_t)l2 * BB + bs[k]];
                        acc[k] += Tl[j * CC2 + s1[k] * CCH + s2];
                    }
                }
            } else {
                for (int j = 0; j < nj; ++j) {
                    const int l2 = l2s + j;
#pragma unroll
                    for (int k = 0; k < BPT; ++k) {
                        int s2 = seqT[(size_t)l2 * BB + bs[k]];
                        acc[k] += Tl[j * CC2 + s1[k] * CCH + s2];
                    }
                }
            }
        }
    }
#pragma unroll
    for (int k = 0; k < BPT; ++k)
        atomicAdd(&out[bs[k]], acc[k]);
}

extern "C" void kernel_launch(void* const* d_in, const int* in_sizes, int n_in,
                              void* d_out, int out_size, void* d_ws, size_t ws_size,
                              hipStream_t stream) {
    const float* x_lc       = (const float*)d_in[0];
    const float* theta_0    = (const float*)d_in[1];
    const float* theta_lc   = (const float*)d_in[2];
    const float* theta_lclc = (const float*)d_in[3];
    // d_in[4] = mask (bool) — implicit: we only iterate l2 > l1.
    float* out = (float*)d_out;
    unsigned char* seqT = (unsigned char*)d_ws;   // L*B = 1 MB

    k_prepare<<<dim3(BB), dim3(256), 0, stream>>>(x_lc, theta_0, theta_lc, seqT, out);
    k_quad<<<dim3(NTILES, NGROUPS), dim3(QTHREADS), 0, stream>>>(theta_lclc, seqT, out);
}

// Round 2
// 90.359 us; speedup vs baseline: 1.3634x; 1.3634x over previous
//
#include <hip/hip_runtime.h>

#define LPOS 256
#define CCH 20
#define BB 4096
#define LC 5120  // LPOS*CCH

// ---------------- Kernel 1: seq extraction + linear term -------------------
__global__ __launch_bounds__(256) void k_prepare(
    const float* __restrict__ x_lc, const float* __restrict__ theta_0,
    const float* __restrict__ theta_lc, unsigned char* __restrict__ seqT,
    float* __restrict__ out)
{
    const int b = blockIdx.x;
    const int l = threadIdx.x;
    const float* xp = x_lc + (size_t)b * LC + (size_t)l * CCH;
    const float4* xp4 = reinterpret_cast<const float4*>(xp);
    float v[CCH];
#pragma unroll
    for (int q = 0; q < 5; ++q) {
        float4 t = xp4[q];
        v[q * 4 + 0] = t.x; v[q * 4 + 1] = t.y;
        v[q * 4 + 2] = t.z; v[q * 4 + 3] = t.w;
    }
    int s = 0; float best = v[0];
#pragma unroll
    for (int c = 1; c < CCH; ++c) { if (v[c] > best) { best = v[c]; s = c; } }

    seqT[(size_t)l * BB + b] = (unsigned char)s;

    float lin = theta_lc[l * CCH + s];
#pragma unroll
    for (int off = 32; off > 0; off >>= 1) lin += __shfl_down(lin, off, 64);
    __shared__ float partial[4];
    const int wave = threadIdx.x >> 6;
    const int lane = threadIdx.x & 63;
    if (lane == 0) partial[wave] = lin;
    __syncthreads();
    if (threadIdx.x == 0)
        out[b] = theta_0[0] + partial[0] + partial[1] + partial[2] + partial[3];
}

// ---------------- Kernel 2: masked pairwise quadratic form -----------------
// One-hot x + strict l2 > l1 makes the mask implicit; quad[b] is 32640
// table lookups. Block (tile, g): batches [tile*512, tile*512+512),
// rows l1 in {g, 254-g} (256 pairs/block, balanced). Per 16-wide l2 chunk,
// stage the 20 x (16*20) subtable [c1][j*20+c2] into LDS with pure float4
// copies, then each thread gathers 16 values for its batch.
#define QTHREADS 512
#define TILEB 512
#define NTILES (BB / TILEB)      // 8
#define NGROUPS 128
#define L2CHUNK 16
#define SROW 344                 // 16*20=320 payload + 24 pad (344%32==24)
#define SROW4 (SROW / 4)         // 86
#define VEC4_PER_ROW 80          // 320/4
#define TOTVEC4 (CCH * VEC4_PER_ROW)  // 1600
#define LC4 (LC / 4)             // 1280

__global__ __launch_bounds__(QTHREADS) void k_quad(
    const float* __restrict__ Theta,          // (5120, 5120), row-major
    const unsigned char* __restrict__ seqT,   // (L, B)
    float* __restrict__ out)
{
    __shared__ float4 Tl4[CCH * SROW4];
    float* Tl = reinterpret_cast<float*>(Tl4);

    const int tile = blockIdx.x;   // 0..NTILES-1
    const int g    = blockIdx.y;   // 0..127
    const int tid  = threadIdx.x;
    const int b    = tile * TILEB + tid;

    float acc = 0.f;

    int l1list[2] = { g, 254 - g };
    const int nl1 = (g == 127) ? 1 : 2;

    for (int i = 0; i < nl1; ++i) {
        const int l1 = l1list[i];
        const int s1 = seqT[(size_t)l1 * BB + b];
        const int base = s1 * SROW;
        const float4* Trow4 =
            reinterpret_cast<const float4*>(Theta + (size_t)(l1 * CCH) * LC);

        for (int l2s = l1 + 1; l2s < LPOS; l2s += L2CHUNK) {
            const int nj = min(L2CHUNK, LPOS - l2s);
            __syncthreads();  // previous chunk's gathers complete
            // Stage: 20 rows x 320 contiguous floats (over-stage ragged tail;
            // provably in-bounds of the 5120^2 tensor).
#pragma unroll
            for (int q = 0; q < 4; ++q) {
                int t = tid + q * QTHREADS;
                if (t < TOTVEC4) {
                    int r = t / VEC4_PER_ROW;          // c1
                    int off = t - r * VEC4_PER_ROW;
                    Tl4[r * SROW4 + off] = Trow4[r * LC4 + l2s * 5 + off];
                }
            }
            __syncthreads();
            if (nj == L2CHUNK) {
#pragma unroll
                for (int j = 0; j < L2CHUNK; ++j) {
                    int s2 = seqT[(size_t)(l2s + j) * BB + b];
                    acc += Tl[base + j * CCH + s2];
                }
            } else {
                for (int j = 0; j < nj; ++j) {
                    int s2 = seqT[(size_t)(l2s + j) * BB + b];
                    acc += Tl[base + j * CCH + s2];
                }
            }
        }
    }
    atomicAdd(&out[b], acc);
}

extern "C" void kernel_launch(void* const* d_in, const int* in_sizes, int n_in,
                              void* d_out, int out_size, void* d_ws, size_t ws_size,
                              hipStream_t stream) {
    const float* x_lc       = (const float*)d_in[0];
    const float* theta_0    = (const float*)d_in[1];
    const float* theta_lc   = (const float*)d_in[2];
    const float* theta_lclc = (const float*)d_in[3];
    // d_in[4] = mask (bool) — implicit: we only iterate l2 > l1.
    float* out = (float*)d_out;
    unsigned char* seqT = (unsigned char*)d_ws;   // L*B = 1 MB

    k_prepare<<<dim3(BB), dim3(256), 0, stream>>>(x_lc, theta_0, theta_lc, seqT, out);
    k_quad<<<dim3(NTILES, NGROUPS), dim3(QTHREADS), 0, stream>>>(theta_lclc, seqT, out);
}

// Round 3
// 89.455 us; speedup vs baseline: 1.3772x; 1.0101x over previous
//
#include <hip/hip_runtime.h>

#define LPOS 256
#define CCH 20
#define BB 4096
#define LC 5120  // LPOS*CCH

// ---------------- Kernel 1: seq extraction + linear term -------------------
// One block per batch b; thread = position l. Writes seqB[b*256 + l] (u8,
// batch-major so k_quad can grab 16 positions per uint4) and
// out[b] = theta0 + sum_l theta_lc[l, s_l].
__global__ __launch_bounds__(256) void k_prepare(
    const float* __restrict__ x_lc, const float* __restrict__ theta_0,
    const float* __restrict__ theta_lc, unsigned char* __restrict__ seqB,
    float* __restrict__ out)
{
    const int b = blockIdx.x;
    const int l = threadIdx.x;
    const float* xp = x_lc + (size_t)b * LC + (size_t)l * CCH;
    const float4* xp4 = reinterpret_cast<const float4*>(xp);
    float v[CCH];
#pragma unroll
    for (int q = 0; q < 5; ++q) {
        float4 t = xp4[q];
        v[q * 4 + 0] = t.x; v[q * 4 + 1] = t.y;
        v[q * 4 + 2] = t.z; v[q * 4 + 3] = t.w;
    }
    int s = 0; float best = v[0];
#pragma unroll
    for (int c = 1; c < CCH; ++c) { if (v[c] > best) { best = v[c]; s = c; } }

    seqB[(size_t)b * LPOS + l] = (unsigned char)s;

    float lin = theta_lc[l * CCH + s];
#pragma unroll
    for (int off = 32; off > 0; off >>= 1) lin += __shfl_down(lin, off, 64);
    __shared__ float partial[4];
    const int wave = threadIdx.x >> 6;
    const int lane = threadIdx.x & 63;
    if (lane == 0) partial[wave] = lin;
    __syncthreads();
    if (threadIdx.x == 0)
        out[b] = theta_0[0] + partial[0] + partial[1] + partial[2] + partial[3];
}

// ---------------- Kernel 2: masked pairwise quadratic form -----------------
// One-hot x + strict l2 > l1 makes the mask implicit. Block (tile, g):
// batches [tile*512, +512), rows l1 in {g, 254-g} (256 pairs/block).
// l2 is processed in ABSOLUTE 16-aligned chunks m (l2 = 16m+j); the 20x320
// subtable [c1][j*20+c2] is staged to LDS with pure float4 copies (chunks
// land exactly on Theta row ends: 16m*20+320 <= 5120). All 16 s2 indices of
// a chunk come from ONE uint4 load of batch-major seqB.
#define QTHREADS 512
#define TILEB 512
#define NTILES (BB / TILEB)      // 8
#define NGROUPS 128
#define SROW 344                 // 320 payload + 24 pad (344%32==24 spreads banks)
#define SROW4 (SROW / 4)         // 86
#define LC4 (LC / 4)             // 1280

__global__ __launch_bounds__(QTHREADS) void k_quad(
    const float* __restrict__ Theta,          // (5120, 5120), row-major
    const unsigned char* __restrict__ seqB,   // (B, L)
    float* __restrict__ out)
{
    __shared__ float4 Tl4[CCH * SROW4];
    float* Tl = reinterpret_cast<float*>(Tl4);

    const int tile = blockIdx.x;
    const int g    = blockIdx.y;
    const int tid  = threadIdx.x;
    const int b    = tile * TILEB + tid;

    const unsigned char* sb = seqB + (size_t)b * LPOS;
    const uint4* sb4 = reinterpret_cast<const uint4*>(sb);

    float acc = 0.f;

    int l1list[2] = { g, 254 - g };
    const int nl1 = (g == 127) ? 1 : 2;

    for (int i = 0; i < nl1; ++i) {
        const int l1 = l1list[i];
        const int s1 = sb[l1];
        const int base = s1 * SROW;
        const float4* Trow4 =
            reinterpret_cast<const float4*>(Theta + (size_t)(l1 * CCH) * LC);

        const int m0  = (l1 + 1) >> 4;
        const int jlo = (l1 + 1) & 15;

        for (int m = m0; m < 16; ++m) {
            __syncthreads();  // previous chunk's gathers complete
            // Stage 20 rows x 80 float4 (1600 vec4 total; 3 full sweeps + tail)
#pragma unroll
            for (int q = 0; q < 3; ++q) {
                int t = tid + q * QTHREADS;       // < 1536, r <= 19
                int r = t / 80;
                int off = t - r * 80;
                Tl4[r * SROW4 + off] = Trow4[r * LC4 + m * 80 + off];
            }
            {
                int t = tid + 1536;
                if (t < 1600)
                    Tl4[19 * SROW4 + (t - 1520)] = Trow4[19 * LC4 + m * 80 + (t - 1520)];
            }
            uint4 sq = sb4[m];   // issue during staging; used after barrier
            __syncthreads();

            const unsigned w0 = sq.x, w1 = sq.y, w2 = sq.z, w3 = sq.w;
            if (m == m0 && jlo) {
                // ragged first chunk: branch-free predicate, indices static
#pragma unroll
                for (int j = 0; j < 16; ++j) {
                    const unsigned w = (j < 4) ? w0 : (j < 8) ? w1 : (j < 12) ? w2 : w3;
                    int s2 = (w >> ((j & 3) * 8)) & 0xFF;
                    float val = Tl[base + j * CCH + s2];
                    acc += (j >= jlo) ? val : 0.f;
                }
            } else {
#pragma unroll
                for (int j = 0; j < 16; ++j) {
                    const unsigned w = (j < 4) ? w0 : (j < 8) ? w1 : (j < 12) ? w2 : w3;
                    int s2 = (w >> ((j & 3) * 8)) & 0xFF;
                    acc += Tl[base + j * CCH + s2];
                }
            }
        }
    }
    atomicAdd(&out[b], acc);
}

extern "C" void kernel_launch(void* const* d_in, const int* in_sizes, int n_in,
                              void* d_out, int out_size, void* d_ws, size_t ws_size,
                              hipStream_t stream) {
    const float* x_lc       = (const float*)d_in[0];
    const float* theta_0    = (const float*)d_in[1];
    const float* theta_lc   = (const float*)d_in[2];
    const float* theta_lclc = (const float*)d_in[3];
    // d_in[4] = mask (bool) — implicit: we only iterate l2 > l1.
    float* out = (float*)d_out;
    unsigned char* seqB = (unsigned char*)d_ws;   // B*L = 1 MB

    k_prepare<<<dim3(BB), dim3(256), 0, stream>>>(x_lc, theta_0, theta_lc, seqB, out);
    k_quad<<<dim3(NTILES, NGROUPS), dim3(QTHREADS), 0, stream>>>(theta_lclc, seqB, out);
}